// Round 1
// 55.269 us; speedup vs baseline: 1.1380x; 1.1380x over previous
//
#include <hip/hip_runtime.h>

#define B_ 2
#define N_ 16384
#define M_ 8192
#define BLK 256
#define TN 8
#define CHUNK 256

typedef float f32x2 __attribute__((ext_vector_type(2)));
typedef float f32x4 __attribute__((ext_vector_type(4)));

// proven on HW in round 3 (all-VGPR operands)
__device__ inline f32x2 pk_fma(f32x2 a, f32x2 b, f32x2 c) {
    f32x2 d;
    asm("v_pk_fma_f32 %0, %1, %2, %3" : "=v"(d) : "v"(a), "v"(b), "v"(c));
    return d;
}
__device__ inline float min3f(float a, float b, float c) {
    float d;
    asm("v_min3_f32 %0, %1, %2, %3" : "=v"(d) : "v"(a), "v"(b), "v"(c));
    return d;
}

// ---------------- reductions ----------------

__device__ inline float blk_reduce_max(float v, float* red) {
    #pragma unroll
    for (int off = 32; off; off >>= 1) v = fmaxf(v, __shfl_xor(v, off));
    int wid = threadIdx.x >> 6;
    int lane = threadIdx.x & 63;
    int nw = blockDim.x >> 6;
    if (lane == 0) red[wid] = v;
    __syncthreads();
    if (wid == 0) {
        v = (lane < nw) ? red[lane] : -3.402823466e38f;
        #pragma unroll
        for (int off = 32; off; off >>= 1) v = fmaxf(v, __shfl_xor(v, off));
        if (lane == 0) red[0] = v;
    }
    __syncthreads();
    v = red[0];
    __syncthreads();
    return v;
}

__device__ inline float blk_reduce_sum(float v, float* red) {
    #pragma unroll
    for (int off = 32; off; off >>= 1) v += __shfl_xor(v, off);
    int wid = threadIdx.x >> 6;
    int lane = threadIdx.x & 63;
    int nw = blockDim.x >> 6;
    if (lane == 0) red[wid] = v;
    __syncthreads();
    if (wid == 0) {
        v = (lane < nw) ? red[lane] : 0.0f;
        #pragma unroll
        for (int off = 32; off; off >>= 1) v += __shfl_xor(v, off);
        if (lane == 0) red[0] = v;
    }
    __syncthreads();
    v = red[0];
    __syncthreads();
    return v;
}

// ---------------- kernels ----------------

// grid = (B_*N_)/256 = 128 blocks. Also computes per-wave partial maxes of the
// weights (raceless: each wave writes its own slot), so finalize can skip the
// full-N max pass.
__global__ __launch_bounds__(256) void init_ws(const float* __restrict__ wts,
                                               unsigned int* min1, unsigned int* min2,
                                               float* __restrict__ wmax_part,
                                               float* out) {
    int i = blockIdx.x * 256 + threadIdx.x;
    if (i < B_ * N_) min1[i] = 0x7F7FFFFFu;  // FLT_MAX bits
    if (i < B_ * M_) min2[i] = 0x7F7FFFFFu;
    if (i == 0) out[0] = 0.0f;

    // i always < B_*N_ with this grid; wts is (B, N) flat.
    float v = wts[i];
    #pragma unroll
    for (int off = 32; off; off >>= 1) v = fmaxf(v, __shfl_xor(v, off));
    if ((threadIdx.x & 63) == 0)
        wmax_part[blockIdx.x * 4 + (threadIdx.x >> 6)] = v;  // 4 waves/block
}

// Fused both-direction pairwise-min sweep, packed-fp32 inner loop.
//   blocks [0,512):    owners = points1 rows (N), scan points2 (M)
//   blocks [512,1024): owners = points2 rows (M), scan points1 (N)
// TN=8 (owners/thread) -> 1024 blocks = 4 blocks/CU = 4 waves/SIMD, double the
// previous occupancy (grid-limited at TN=16). Atomic count is unchanged
// (atomics = NA*bins*B, independent of TN); VALU slots/pair unchanged.
// LDS stores CHUNK staged points as pairs {x0,x1,y0,y1 | z0,z1,w0,w1} with
// (x,y,z) pre-scaled by -2 and w = ||p||^2, read as 2x ds_read_b128 per pair.
__global__ __launch_bounds__(BLK) void min_pairwise_all(
        const float* __restrict__ p1, const float* __restrict__ p2,
        unsigned int* __restrict__ min1, unsigned int* __restrict__ min2) {
    __shared__ f32x4 sh4[CHUNK];   // (CHUNK/2 pairs) * 2 quads = 4 KiB

    int bid = blockIdx.x;
    const float* pa;
    const float* pb;
    unsigned int* mins;
    int NA, NB, bx, bin, b;
    if (bid < 512) {
        bx = bid & 7;               // 8 x-blocks * 2048 owners = 16384
        bin = (bid >> 3) & 31;      // 32 bins * 256 = 8192 scanned
        b = bid >> 8;
        pa = p1; pb = p2; mins = min1; NA = N_; NB = M_;
    } else {
        int t = bid - 512;
        bx = t & 3;                 // 4 x-blocks * 2048 owners = 8192
        bin = (t >> 2) & 63;        // 64 bins * 256 = 16384 scanned
        b = t >> 8;
        pa = p2; pb = p1; mins = min2; NA = M_; NB = N_;
    }

    // stage + pre-transform one chunk of the scanned set (pair-interleaved)
    {
        const float* pbb = pb + ((size_t)b * NB + bin * CHUNK) * 3;
        int i = threadIdx.x;
        float gx = pbb[3 * i], gy = pbb[3 * i + 1], gz = pbb[3 * i + 2];
        float* base = (float*)&sh4[(i >> 1) * 2] + (i & 1);
        base[0] = -2.0f * gx;
        base[2] = -2.0f * gy;
        base[4] = -2.0f * gz;
        base[6] = fmaf(gx, gx, fmaf(gy, gy, gz * gz));
    }
    __syncthreads();

    // owners: load once, duplicate into both packed halves (one-time cost)
    const float* pab = pa + (size_t)b * NA * 3;
    const int nbase = bx * (BLK * TN) + threadIdx.x;

    f32x2 X[TN], Y[TN], Z[TN];
    float mn[TN];
    #pragma unroll
    for (int j = 0; j < TN; j++) {
        int n = nbase + j * BLK;
        float x = pab[3 * n], y = pab[3 * n + 1], z = pab[3 * n + 2];
        X[j] = (f32x2){x, x};
        Y[j] = (f32x2){y, y};
        Z[j] = (f32x2){z, z};
        mn[j] = 3.402823466e38f;
    }

    #pragma unroll 2
    for (int p = 0; p < CHUNK / 2; p++) {
        f32x4 lo = sh4[2 * p];
        f32x4 hi = sh4[2 * p + 1];
        f32x2 Qx = __builtin_shufflevector(lo, lo, 0, 1);
        f32x2 Qy = __builtin_shufflevector(lo, lo, 2, 3);
        f32x2 Qz = __builtin_shufflevector(hi, hi, 0, 1);
        f32x2 Qw = __builtin_shufflevector(hi, hi, 2, 3);
        #pragma unroll
        for (int j = 0; j < TN; j++) {
            f32x2 v = pk_fma(Z[j], Qz, Qw);
            v = pk_fma(Y[j], Qy, v);
            v = pk_fma(X[j], Qx, v);
            mn[j] = min3f(mn[j], v.x, v.y);
        }
    }

    #pragma unroll
    for (int j = 0; j < TN; j++) {
        int n = nbase + j * BLK;
        float sqa = fmaf(X[j].x, X[j].x, fmaf(Y[j].x, Y[j].x, Z[j].x * Z[j].x));
        // squared distances are non-negative: float bits order as uint
        atomicMin(&mins[(size_t)b * NA + n], __float_as_uint(mn[j] + sqa));
    }
}

__global__ __launch_bounds__(1024) void finalize_kernel(
        const float* __restrict__ wts,
        const float* __restrict__ min1,
        const float* __restrict__ min2,
        const float* __restrict__ wmax_part,
        float* __restrict__ out) {
    __shared__ float red[16];
    int b = blockIdx.x;
    const float* wb = wts + b * N_;
    const float* m1 = min1 + b * N_;
    const float* m2 = min2 + b * M_;

    // max from precomputed per-wave partials (256 per batch)
    float lmax = (threadIdx.x < 256) ? wmax_part[b * 256 + threadIdx.x]
                                     : -3.402823466e38f;
    float gmax = blk_reduce_max(lmax, red);

    float se = 0.0f, swm = 0.0f;
    for (int i = threadIdx.x; i < N_ / 4; i += blockDim.x) {
        f32x4 w4 = ((const f32x4*)wb)[i];
        f32x4 m4 = ((const f32x4*)m1)[i];
        #pragma unroll
        for (int k = 0; k < 4; k++) {
            float e = expf(w4[k] - gmax);
            se += e;
            swm += e * m4[k];
        }
    }
    float tse = blk_reduce_sum(se, red);
    float tswm = blk_reduce_sum(swm, red);

    float sm2 = 0.0f;
    for (int i = threadIdx.x; i < M_ / 4; i += blockDim.x) {
        f32x4 m4 = ((const f32x4*)m2)[i];
        sm2 += (m4.x + m4.y) + (m4.z + m4.w);
    }
    float tsm2 = blk_reduce_sum(sm2, red);

    if (threadIdx.x == 0)
        atomicAdd(out, (tswm / tse + tsm2 * (1.0f / (float)M_)) * (1.0f / (float)B_));
}

// ---------------- launch ----------------

extern "C" void kernel_launch(void* const* d_in, const int* in_sizes, int n_in,
                              void* d_out, int out_size, void* d_ws, size_t ws_size,
                              hipStream_t stream) {
    const float* p1  = (const float*)d_in[0];  // (B, N, 3)
    const float* p2  = (const float*)d_in[1];  // (B, M, 3)
    const float* wts = (const float*)d_in[2];  // (B, N)
    float* out = (float*)d_out;

    unsigned int* min1 = (unsigned int*)d_ws;        // B*N
    unsigned int* min2 = min1 + B_ * N_;             // B*M
    float* wmax_part = (float*)(min2 + B_ * M_);     // 128 blocks * 4 waves = 512

    init_ws<<<dim3((B_ * N_) / 256), dim3(256), 0, stream>>>(wts, min1, min2,
                                                             wmax_part, out);
    min_pairwise_all<<<dim3(1024), dim3(BLK), 0, stream>>>(p1, p2, min1, min2);
    finalize_kernel<<<dim3(B_), dim3(1024), 0, stream>>>(
        wts, (const float*)min1, (const float*)min2, wmax_part, out);
}